// Round 6
// baseline (16422.214 us; speedup 1.0000x reference)
//
#include <hip/hip_runtime.h>
#include <stdint.h>

#define DEV __device__ __forceinline__

typedef unsigned short u16;
typedef __attribute__((ext_vector_type(8))) __bf16 bf16x8;
typedef __attribute__((ext_vector_type(4))) float f32x4;

// ---------- helpers ----------
DEV float bf2f(u16 u) {
    unsigned v = ((unsigned)u) << 16;
    float f;
    __builtin_memcpy(&f, &v, 4);
    return f;
}
DEV u16 f2bf(float x) {
    unsigned u;
    __builtin_memcpy(&u, &x, 4);
    return (u16)((u + 0x7FFFu + ((u >> 16) & 1u)) >> 16);
}
DEV float sigf(float x) {
    float e = __builtin_amdgcn_exp2f(-1.442695040888963f * x);
    return __builtin_amdgcn_rcpf(1.0f + e);
}
DEV f32x4 mfma16(bf16x8 a, bf16x8 b, f32x4 c) {
    return __builtin_amdgcn_mfma_f32_16x16x32_bf16(a, b, c, 0, 0, 0);
}

static constexpr size_t XROW = 1536;
static constexpr size_t XE = 32768 * XROW;  // per-encode xi elements
static constexpr float NL2E = -1.442695040888963f;  // -log2(e), r/z prescale
static constexpr float P2L2E = 2.885390081777927f;  // 2*log2(e), n prescale

// ---------- fp32 -> bf16 weight conversion (with per-layer restride) ----------
__global__ void convert_w(const float* __restrict__ src, u16* __restrict__ dst,
                          int n_per, int stride_l, int total) {
    int idx = blockIdx.x * 256 + threadIdx.x;
    if (idx >= total) return;
    int l = idx / n_per;
    int r = idx - l * n_per;
    dst[(size_t)l * stride_l + r] = f2bf(src[idx]);
}

// whh with per-gate trans-prescale: rows [0,512) * -log2e, rows [512,768) * 2log2e
__global__ void convert_whh(const float* __restrict__ src, u16* __restrict__ dst, int dir_ofs) {
    int idx = blockIdx.x * 256 + threadIdx.x;  // < 786432
    int l = idx / 196608;
    int r = idx - l * 196608;
    float S = ((r >> 16) < 2) ? NL2E : P2L2E;
    dst[(size_t)l * 393216 + dir_ofs + r] = f2bf(src[idx] * S);
}

// wih with ln gamma + per-gate trans-prescale folded in
__global__ void convert_wih(const float* __restrict__ src, const float* __restrict__ lng,
                            u16* __restrict__ dst, int dir_ofs) {
    int idx = blockIdx.x * 256 + threadIdx.x;  // < 786432
    int l = idx / 196608;
    int r = idx - l * 196608;
    int k = idx & 255;
    float S = ((r >> 16) < 2) ? NL2E : P2L2E;
    dst[(size_t)l * 393216 + dir_ofs + r] = f2bf(src[idx] * lng[l * 256 + k] * S);
}

// per-(layer,n) LN-fold head vectors: e_n = S*sum_k W*g ; c_n = S*(sum_k W*beta + bih (+bhh r,z))
__global__ void head_vecs_kernel(const float* __restrict__ wihf, const float* __restrict__ wihr,
                                 const float* __restrict__ bihf, const float* __restrict__ bihr,
                                 const float* __restrict__ bhhf, const float* __restrict__ bhhr,
                                 const float* __restrict__ lng, const float* __restrict__ lnb,
                                 float* __restrict__ env, float* __restrict__ cvec) {
    int w = threadIdx.x >> 6, lane = threadIdx.x & 63;
    int row = blockIdx.x * 4 + w;  // [0, 6144)
    int l = row / 1536;
    int n1536 = row - l * 1536;
    int dir = n1536 >= 768;
    int n = n1536 - dir * 768;  // [0,768), gate-stacked r|z|n
    const float* W = (dir ? wihr : wihf) + ((size_t)l * 768 + n) * 256 + lane * 4;
    float4 wv = *(const float4*)W;
    float4 gv = *(const float4*)(lng + l * 256 + lane * 4);
    float4 bv = *(const float4*)(lnb + l * 256 + lane * 4);
    float es = wv.x * gv.x + wv.y * gv.y + wv.z * gv.z + wv.w * gv.w;
    float cs = wv.x * bv.x + wv.y * bv.y + wv.z * bv.z + wv.w * bv.w;
#pragma unroll
    for (int off = 1; off < 64; off <<= 1) {
        es += __shfl_xor(es, off);
        cs += __shfl_xor(cs, off);
    }
    if (lane == 0) {
        float S = (n < 512) ? NL2E : P2L2E;
        float c = cs + (dir ? bihr : bihf)[l * 768 + n];
        if (n < 512) c += (dir ? bhhr : bhhf)[l * 768 + n];  // bhh_n stays in the scan
        env[row] = es * S;
        cvec[row] = c * S;
    }
}

// ---------- embedding (+ reverse-complement encode), h bf16 [e][b][s][k] ----------
__global__ void embed_kernel(const int* __restrict__ tok, const float* __restrict__ emb,
                             const float* __restrict__ pos, u16* __restrict__ h) {
    int row = blockIdx.x;  // e*32768 + b*1024 + s
    int k = threadIdx.x;
    int e = row >> 15;
    int rem = row & 32767;
    int b = rem >> 10;
    int s = rem & 1023;
    int t0 = (e == 0) ? tok[b * 1024 + s] : tok[b * 1024 + (1023 - s)];
    if (e == 1) t0 = (t0 < 4) ? (3 - t0) : 4;  // RC map {3,2,1,0,4}
    h[(size_t)row * 256 + k] = f2bf(emb[t0 * 256 + k] + pos[s * 256 + k]);
}

// ---------- per-row LN stats (mean, rstd) in m-order ----------
__global__ void ln_stats_kernel(const u16* __restrict__ h, float2* __restrict__ stats) {
    int w = threadIdx.x >> 6, lane = threadIdx.x & 63;
    int row = blockIdx.x * 4 + w;  // e*32768 + b*1024 + s
    int e = row >> 15;
    int rem = row & 32767;
    int b = rem >> 10;
    int s = rem & 1023;
    ushort4 v = *(const ushort4*)(h + (size_t)row * 256 + lane * 4);
    float x0 = bf2f(v.x), x1 = bf2f(v.y), x2 = bf2f(v.z), x3 = bf2f(v.w);
    float sum = x0 + x1 + x2 + x3;
    float sq = x0 * x0 + x1 * x1 + x2 * x2 + x3 * x3;
#pragma unroll
    for (int off = 1; off < 64; off <<= 1) {
        sum += __shfl_xor(sum, off);
        sq += __shfl_xor(sq, off);
    }
    if (lane == 0) {
        float mean = sum * (1.0f / 256.0f);
        float var = sq * (1.0f / 256.0f) - mean * mean;
        stats[e * 32768 + s * 32 + b] = make_float2(mean, rsqrtf(var + 1e-5f));
    }
}

// ---------- BT-GEMM: C[m][n] = sum_k A[m][k]*B[n][k], bf16 in / fp32 acc ----------
// OP 0: xi (N=1536,K=256): A = h (gathered b,s), LN folded via stats + env/cvec; out -> xi
// OP 1: gate(N=256,K=512): A = [f|r] from xi cols [0:256)/[768:1024); c -> xi cols [256:512)
// OP 2: out (N=256,K=256): A = c from xi cols [256:512); h += C + bias (bf16 RMW)
template <int OP>
__global__ __launch_bounds__(256, 2) void gemm_bt(
    const u16* __restrict__ hin, const u16* __restrict__ Bw,
    const float* __restrict__ bias0, const float* __restrict__ bias1,
    u16* xibuf, const float2* __restrict__ stats, u16* hres) {
    constexpr int KK = (OP == 1) ? 512 : 256;
    constexpr int NKB = KK / 64;
    __shared__ __align__(16) u16 As[2][128 * 64];
    __shared__ __align__(16) u16 Bs[2][128 * 64];
    const int tid = threadIdx.x;
    const int lane = tid & 63, w = tid >> 6;
    const int l15 = lane & 15, q = lane >> 4;
    const int l8 = lane & 7, r8 = lane >> 3;
    const int e = blockIdx.z;
    const int m0 = blockIdx.x * 128, n0 = blockIdx.y * 128;
    const int wm = w & 1, wn = w >> 1;

    uint4 ra[4], rb[4];
    auto loadS = [&](int kb) {
#pragma unroll
        for (int i = 0; i < 4; ++i) {
            int row = w * 32 + i * 8 + r8;
            int c = l8 ^ (row & 7);
            int mrow = m0 + row;
            const u16* ap;
            if constexpr (OP == 0) {
                int bb = mrow & 31, ss = mrow >> 5;
                ap = hin + ((size_t)e * 32768 + bb * 1024 + ss) * 256 + kb * 64;
            } else if constexpr (OP == 1) {
                int colbase = (kb >= 4) ? 768 : 0;
                ap = xibuf + (size_t)e * XE + (size_t)mrow * XROW + colbase + (kb & 3) * 64;
            } else {
                ap = xibuf + (size_t)e * XE + (size_t)mrow * XROW + 256 + kb * 64;
            }
            ra[i] = *(const uint4*)(ap + c * 8);
            rb[i] = *(const uint4*)(Bw + (size_t)(n0 + row) * KK + kb * 64 + c * 8);
        }
    };
    auto writeS = [&](int buf) {
#pragma unroll
        for (int i = 0; i < 4; ++i) {
            int row = w * 32 + i * 8 + r8;
            *(uint4*)&As[buf][row * 64 + l8 * 8] = ra[i];
            *(uint4*)&Bs[buf][row * 64 + l8 * 8] = rb[i];
        }
    };

    f32x4 acc[4][4];
#pragma unroll
    for (int i = 0; i < 4; ++i)
#pragma unroll
        for (int j = 0; j < 4; ++j) acc[i][j] = (f32x4){0.f, 0.f, 0.f, 0.f};

    loadS(0);
    writeS(0);
    for (int kb = 0; kb < NKB; ++kb) {
        if (kb + 1 < NKB) loadS(kb + 1);
        __syncthreads();
        const int buf = kb & 1;
#pragma unroll
        for (int kt = 0; kt < 2; ++kt) {
            bf16x8 af[4], bfr[4];
#pragma unroll
            for (int i = 0; i < 4; ++i) {
                int rowa = wm * 64 + i * 16 + l15;
                int rowb = wn * 64 + i * 16 + l15;
                int c = kt * 4 + q;
                af[i] = *(const bf16x8*)&As[buf][rowa * 64 + (c ^ (rowa & 7)) * 8];
                bfr[i] = *(const bf16x8*)&Bs[buf][rowb * 64 + (c ^ (rowb & 7)) * 8];
            }
#pragma unroll
            for (int i = 0; i < 4; ++i)
#pragma unroll
                for (int j = 0; j < 4; ++j) acc[i][j] = mfma16(af[i], bfr[j], acc[i][j]);
        }
        if (kb + 1 < NKB) writeS((kb + 1) & 1);
    }

#pragma unroll
    for (int i = 0; i < 4; ++i) {
        const int mb = m0 + wm * 64 + i * 16 + q * 4;
        float2 st[4];
        if constexpr (OP == 0) {
#pragma unroll
            for (int r = 0; r < 4; ++r) st[r] = stats[e * 32768 + mb + r];
        }
#pragma unroll
        for (int jt = 0; jt < 4; ++jt) {
            const int nn = n0 + wn * 64 + jt * 16 + l15;
            f32x4 a = acc[i][jt];
            if constexpr (OP == 0) {
                const float en = bias0[nn], cn = bias1[nn];
#pragma unroll
                for (int r = 0; r < 4; ++r) {
                    float val = a[r] * st[r].y - st[r].x * st[r].y * en + cn;
                    xibuf[(size_t)e * XE + (size_t)(mb + r) * XROW + nn] = f2bf(val);
                }
            } else if constexpr (OP == 1) {
                const float bs = bias0[nn];
#pragma unroll
                for (int r = 0; r < 4; ++r) {
                    u16* xr_ = xibuf + (size_t)e * XE + (size_t)(mb + r) * XROW;
                    float gg = sigf(a[r] + bs);
                    float fv = bf2f(xr_[nn]), rv = bf2f(xr_[768 + nn]);
                    xr_[256 + nn] = f2bf(gg * fv + (1.0f - gg) * rv);
                }
            } else {
                const float bs = bias0[nn];
#pragma unroll
                for (int r = 0; r < 4; ++r) {
                    const int mm = mb + r;
                    size_t idx = ((size_t)e * 32768 + (size_t)(mm & 31) * 1024 + (mm >> 5)) * 256 + nn;
                    hres[idx] = f2bf(bf2f(hres[idx]) + a[r] + bs);
                }
            }
        }
    }
}

// ---------- bidirectional GRU scan, single-WG-per-slice ----------
// EXACT round-3 barrier structure (empirically fastest: two plain __syncthreads,
// single stride-264 LDS buffer). Deltas vs R3, all off the barrier protocol:
//  - h_prev kept in registers (no LDS re-read in the epilogue)
//  - transcendental prescale folded into weights (exp2 args straight from accs)
//  - global h-stores BATCHED every 4 steps and issued right after sync2, so
//    sync1 drains nothing on 3/4 steps and month-old stores on the 4th.
__global__ __launch_bounds__(512, 2) void scan_kernel(
    u16* xi, const u16* __restrict__ whh,
    const float* __restrict__ bhhf, const float* __restrict__ bhhr) {
    __shared__ __align__(16) u16 h_lds[16 * 264];  // [m=16][k=256+8 pad]
    const int tid = threadIdx.x;
    const int w = tid >> 6, lane = tid & 63;
    const int l15 = lane & 15, q = lane >> 4;
    const int bid = blockIdx.x;
    const int bh = bid & 1, d = (bid >> 1) & 1, e = bid >> 2;
    const int jb = w * 32;

    // persistent weight A-frags: wf[g][jc][kt], row = g*256 + jb + jc*16 + l15, k = kt*32+q*8
    const u16* W = whh + (size_t)d * 196608;
    bf16x8 wf[3][2][8];
#pragma unroll
    for (int g = 0; g < 3; ++g)
#pragma unroll
        for (int jc = 0; jc < 2; ++jc)
#pragma unroll
            for (int kt = 0; kt < 8; ++kt)
                wf[g][jc][kt] = *(const bf16x8*)(
                    W + (size_t)(g * 256 + jb + jc * 16 + l15) * 256 + kt * 32 + q * 8);

    // n-gate bhh (inside r*(...)), prescaled by 2log2e
    const float* bnp = (d ? bhhr : bhhf) + 512;
    f32x4 bn[2];
#pragma unroll
    for (int jc = 0; jc < 2; ++jc)
#pragma unroll
        for (int r = 0; r < 4; ++r) bn[jc][r] = P2L2E * bnp[jb + jc * 16 + q * 4 + r];

    // xi pointer: row (s*32 + bh*16 + l15), col (d*768 + jb + q*4); imm offsets cover (g,jc)
    const int s0 = d ? 1023 : 0;
    const ptrdiff_t step = (d ? -32 : 32) * (ptrdiff_t)XROW;
    u16* p = xi + (size_t)e * XE + (size_t)(s0 * 32 + bh * 16 + l15) * XROW + d * 768 + jb + q * 4;
    u16* pbase = p;  // base row of the current 4-step store group

    const int lrow = l15 * 264;
    const int jcol = jb + q * 4;

    ushort4 xvv[3][2];
#pragma unroll
    for (int g = 0; g < 3; ++g)
#pragma unroll
        for (int jc = 0; jc < 2; ++jc)
            xvv[g][jc] = *(const ushort4*)(p + g * 256 + jc * 16);

    float hprev[2][4] = {{0.f, 0.f, 0.f, 0.f}, {0.f, 0.f, 0.f, 0.f}};
    ushort4 sbuf[4][2];

    for (int t = 0; t < 1024; ++t) {
        f32x4 a0[2], a1[2], a2[2];
#pragma unroll
        for (int jc = 0; jc < 2; ++jc) {
            a0[jc] = (f32x4){0.f, 0.f, 0.f, 0.f};
            a1[jc] = (f32x4){0.f, 0.f, 0.f, 0.f};
            a2[jc] = bn[jc];
        }
        if (t > 0) {
#pragma unroll
            for (int kt = 0; kt < 8; ++kt) {
                bf16x8 hb = *(const bf16x8*)&h_lds[lrow + kt * 32 + q * 8];
#pragma unroll
                for (int jc = 0; jc < 2; ++jc) {
                    a0[jc] = mfma16(wf[0][jc][kt], hb, a0[jc]);
                    a1[jc] = mfma16(wf[1][jc][kt], hb, a1[jc]);
                    a2[jc] = mfma16(wf[2][jc][kt], hb, a2[jc]);
                }
            }
        }
        // epilogue: lane owns (m=l15, j = jb + jc*16 + q*4 + r); h_prev in regs
        ushort4 hs[2];
#pragma unroll
        for (int jc = 0; jc < 2; ++jc) {
            u16 hr[4];
#pragma unroll
            for (int r = 0; r < 4; ++r) {
                float xr = bf2f(((const u16*)&xvv[0][jc])[r]);  // prescaled by -log2e
                float xz = bf2f(((const u16*)&xvv[1][jc])[r]);  // prescaled by -log2e
                float xn = bf2f(((const u16*)&xvv[2][jc])[r]);  // prescaled by 2log2e
                float rg = __builtin_amdgcn_rcpf(1.0f + __builtin_amdgcn_exp2f(xr + a0[jc][r]));
                float zg = __builtin_amdgcn_rcpf(1.0f + __builtin_amdgcn_exp2f(xz + a1[jc][r]));
                float E = __builtin_amdgcn_exp2f(__builtin_fmaf(rg, a2[jc][r], xn));
                float ng = (E - 1.0f) * __builtin_amdgcn_rcpf(E + 1.0f);
                float h2 = __builtin_fmaf(zg, hprev[jc][r] - ng, ng);
                hprev[jc][r] = h2;
                hr[r] = f2bf(h2);
            }
            hs[jc] = (ushort4){hr[0], hr[1], hr[2], hr[3]};
        }
        sbuf[t & 3][0] = hs[0];
        sbuf[t & 3][1] = hs[1];
        __syncthreads();  // sync1: all reads of h_{t-1} from LDS complete
        *(ushort4*)&h_lds[lrow + jcol] = hs[0];
        *(ushort4*)&h_lds[lrow + jcol + 16] = hs[1];
        __syncthreads();  // sync2: h_t visible to all waves
        if ((t & 3) == 3) {  // flush the 4-step store group (rows already consumed)
#pragma unroll
            for (int k = 0; k < 4; ++k) {
                *(ushort4*)(pbase + (ptrdiff_t)k * step) = sbuf[k][0];
                *(ushort4*)(pbase + (ptrdiff_t)k * step + 16) = sbuf[k][1];
            }
            pbase += 4 * step;
        }
        if (t + 1 < 1024) {
            p += step;
#pragma unroll
            for (int g = 0; g < 3; ++g)
#pragma unroll
                for (int jc = 0; jc < 2; ++jc)
                    xvv[g][jc] = *(const ushort4*)(p + g * 256 + jc * 16);
        }
    }
}

// ---------- final LN + mean-pool + head (projection, LN, exact GELU) ----------
__global__ __launch_bounds__(256) void pool_head_kernel(
    const u16* __restrict__ h, const float* __restrict__ fng, const float* __restrict__ fnb,
    const float* __restrict__ pw, const float* __restrict__ pb,
    const float* __restrict__ plng, const float* __restrict__ plnb, float* __restrict__ out) {
    __shared__ float pacc[4][256];
    __shared__ float pooled[256];
    const int b = blockIdx.x;
    const int tid = threadIdx.x;
    const int w = tid >> 6, lane = tid & 63;
    float a0 = 0.f, a1 = 0.f, a2 = 0.f, a3 = 0.f;
    for (int rr = w; rr < 2048; rr += 4) {
        int e = rr >> 10, s = rr & 1023;
        const u16* src = h + ((size_t)e * 32768 + (size_t)b * 1024 + s) * 256 + lane * 4;
        ushort4 v = *(const ushort4*)src;
        float x0 = bf2f(v.x), x1 = bf2f(v.y), x2 = bf2f(v.z), x3 = bf2f(v.w);
        float sum = x0 + x1 + x2 + x3;
        float sq = x0 * x0 + x1 * x1 + x2 * x2 + x3 * x3;
#pragma unroll
        for (int off = 1; off < 64; off <<= 1) {
            sum += __shfl_xor(sum, off);
            sq += __shfl_xor(sq, off);
        }
        float mean = sum * (1.0f / 256.0f);
        float var = sq * (1.0f / 256.0f) - mean * mean;
        float rs = rsqrtf(var + 1e-5f);
        a0 += (x0 - mean) * rs;
        a1 += (x1 - mean) * rs;
        a2 += (x2 - mean) * rs;
        a3 += (x3 - mean) * rs;
    }
    pacc[w][lane * 4 + 0] = a0;
    pacc[w][lane * 4 + 1] = a1;
    pacc[w][lane * 4 + 2] = a2;
    pacc[w][lane * 4 + 3] = a3;
    __syncthreads();
    {
        int k = tid;
        float t = pacc[0][k] + pacc[1][k] + pacc[2][k] + pacc[3][k];
        pooled[k] = (t * fng[k] + 2048.0f * fnb[k]) * (0.5f / 1024.0f);
    }
    __syncthreads();
    if (tid < 64) {
        float p = pb[tid];
        const float* wrow = pw + tid * 256;
        for (int k = 0; k < 256; ++k) p += pooled[k] * wrow[k];
        float sum = p;
#pragma unroll
        for (int off = 1; off < 64; off <<= 1) sum += __shfl_xor(sum, off);
        float mean = sum * (1.0f / 64.0f);
        float dv = p - mean;
        float sq = dv * dv;
#pragma unroll
        for (int off = 1; off < 64; off <<= 1) sq += __shfl_xor(sq, off);
        float var = sq * (1.0f / 64.0f);
        float y = dv * rsqrtf(var + 1e-5f) * plng[tid] + plnb[tid];
        out[b * 64 + tid] = y * 0.5f * (1.0f + erff(y * 0.70710678118654752f));
    }
}

// ---------- host launch ----------
extern "C" void kernel_launch(void* const* d_in, const int* in_sizes, int n_in,
                              void* d_out, int out_size, void* d_ws, size_t ws_size,
                              hipStream_t stream) {
    (void)in_sizes; (void)n_in; (void)out_size; (void)ws_size;
    const int* tokens = (const int*)d_in[0];
    const float* emb = (const float*)d_in[1];
    const float* pos = (const float*)d_in[2];
    const float* ln_g = (const float*)d_in[3];
    const float* ln_b = (const float*)d_in[4];
    const float* wih_f = (const float*)d_in[5];
    const float* whh_f = (const float*)d_in[6];
    const float* bih_f = (const float*)d_in[7];
    const float* bhh_f = (const float*)d_in[8];
    const float* wih_r = (const float*)d_in[9];
    const float* whh_r = (const float*)d_in[10];
    const float* bih_r = (const float*)d_in[11];
    const float* bhh_r = (const float*)d_in[12];
    const float* wg = (const float*)d_in[13];
    const float* bg = (const float*)d_in[14];
    const float* wo = (const float*)d_in[15];
    const float* bo = (const float*)d_in[16];
    const float* fn_g = (const float*)d_in[17];
    const float* fn_b = (const float*)d_in[18];
    const float* pw = (const float*)d_in[19];
    const float* pb = (const float*)d_in[20];
    const float* pln_g = (const float*)d_in[21];
    const float* pln_b = (const float*)d_in[22];
    float* out = (float*)d_out;
    char* ws = (char*)d_ws;

    // workspace map (bytes) — total ~232 MiB
    u16* h = (u16*)(ws + 0);                    //  32 MiB bf16 [2][32][1024][256]
    u16* xi = (u16*)(ws + 33554432);            // 192 MiB bf16 [2][32768][1536]
    u16* wih_cat = (u16*)(ws + 234881024);      //   3 MiB [L][1536][256] (gamma+S folded)
    u16* whh_bf = (u16*)(ws + 238026752);       //   3 MiB [L][2][768][256] (S folded)
    u16* wg_bf = (u16*)(ws + 241172480);        //   1 MiB [L][256][512]
    u16* wo_bf = (u16*)(ws + 242221056);        // 0.5 MiB [L][256][256]
    float* env = (float*)(ws + 242745344);      //  24 KiB [L][1536]
    float* cvec = (float*)(ws + 242769920);     //  24 KiB [L][1536]
    float2* stats = (float2*)(ws + 242794496);  // 512 KiB [2][32768]

    convert_wih<<<3072, 256, 0, stream>>>(wih_f, ln_g, wih_cat, 0);
    convert_wih<<<3072, 256, 0, stream>>>(wih_r, ln_g, wih_cat, 196608);
    convert_whh<<<3072, 256, 0, stream>>>(whh_f, whh_bf, 0);
    convert_whh<<<3072, 256, 0, stream>>>(whh_r, whh_bf, 196608);
    convert_w<<<2048, 256, 0, stream>>>(wg, wg_bf, 131072, 131072, 524288);
    convert_w<<<1024, 256, 0, stream>>>(wo, wo_bf, 65536, 65536, 262144);
    head_vecs_kernel<<<1536, 256, 0, stream>>>(wih_f, wih_r, bih_f, bih_r, bhh_f, bhh_r,
                                               ln_g, ln_b, env, cvec);
    embed_kernel<<<65536, 256, 0, stream>>>(tokens, emb, pos, h);

    for (int i = 0; i < 4; ++i) {
        ln_stats_kernel<<<16384, 256, 0, stream>>>(h, stats);
        gemm_bt<0><<<dim3(256, 12, 2), 256, 0, stream>>>(
            h, wih_cat + (size_t)i * 393216, env + i * 1536, cvec + i * 1536,
            xi, stats, nullptr);
        scan_kernel<<<8, 512, 0, stream>>>(
            xi, whh_bf + (size_t)i * 393216, bhh_f + i * 768, bhh_r + i * 768);
        gemm_bt<1><<<dim3(256, 2, 2), 256, 0, stream>>>(
            nullptr, wg_bf + (size_t)i * 131072, bg + i * 256, nullptr,
            xi, nullptr, nullptr);
        gemm_bt<2><<<dim3(256, 2, 2), 256, 0, stream>>>(
            nullptr, wo_bf + (size_t)i * 65536, bo + i * 256, nullptr,
            xi, nullptr, h);
    }
    pool_head_kernel<<<32, 256, 0, stream>>>(h, fn_g, fn_b, pw, pb, pln_g, pln_b, out);
}

// Round 7
// 10373.665 us; speedup vs baseline: 1.5831x; 1.5831x over previous
//
#include <hip/hip_runtime.h>
#include <stdint.h>

#define DEV __device__ __forceinline__

typedef unsigned short u16;
typedef __attribute__((ext_vector_type(8))) __bf16 bf16x8;
typedef __attribute__((ext_vector_type(4))) float f32x4;

// ---------- helpers ----------
DEV float bf2f(u16 u) {
    unsigned v = ((unsigned)u) << 16;
    float f;
    __builtin_memcpy(&f, &v, 4);
    return f;
}
DEV u16 f2bf(float x) {
    unsigned u;
    __builtin_memcpy(&u, &x, 4);
    return (u16)((u + 0x7FFFu + ((u >> 16) & 1u)) >> 16);
}
DEV float sigf(float x) {
    float e = __builtin_amdgcn_exp2f(-1.442695040888963f * x);
    return __builtin_amdgcn_rcpf(1.0f + e);
}
DEV f32x4 mfma16(bf16x8 a, bf16x8 b, f32x4 c) {
    return __builtin_amdgcn_mfma_f32_16x16x32_bf16(a, b, c, 0, 0, 0);
}

static constexpr size_t XROW = 1536;
static constexpr size_t XE = 32768 * XROW;  // per-encode xi elements
static constexpr float NL2E = -1.442695040888963f;  // -log2(e), r/z prescale
static constexpr float P2L2E = 2.885390081777927f;  // 2*log2(e), n prescale

// ---------- fp32 -> bf16 weight conversion (with per-layer restride) ----------
__global__ void convert_w(const float* __restrict__ src, u16* __restrict__ dst,
                          int n_per, int stride_l, int total) {
    int idx = blockIdx.x * 256 + threadIdx.x;
    if (idx >= total) return;
    int l = idx / n_per;
    int r = idx - l * n_per;
    dst[(size_t)l * stride_l + r] = f2bf(src[idx]);
}

// whh with per-gate trans-prescale: rows [0,512) * -log2e, rows [512,768) * 2log2e
__global__ void convert_whh(const float* __restrict__ src, u16* __restrict__ dst, int dir_ofs) {
    int idx = blockIdx.x * 256 + threadIdx.x;  // < 786432
    int l = idx / 196608;
    int r = idx - l * 196608;
    float S = ((r >> 16) < 2) ? NL2E : P2L2E;
    dst[(size_t)l * 393216 + dir_ofs + r] = f2bf(src[idx] * S);
}

// wih with ln gamma + per-gate trans-prescale folded in
__global__ void convert_wih(const float* __restrict__ src, const float* __restrict__ lng,
                            u16* __restrict__ dst, int dir_ofs) {
    int idx = blockIdx.x * 256 + threadIdx.x;  // < 786432
    int l = idx / 196608;
    int r = idx - l * 196608;
    int k = idx & 255;
    float S = ((r >> 16) < 2) ? NL2E : P2L2E;
    dst[(size_t)l * 393216 + dir_ofs + r] = f2bf(src[idx] * lng[l * 256 + k] * S);
}

// per-(layer,n) LN-fold head vectors: e_n = S*sum_k W*g ; c_n = S*(sum_k W*beta + bih (+bhh r,z))
__global__ void head_vecs_kernel(const float* __restrict__ wihf, const float* __restrict__ wihr,
                                 const float* __restrict__ bihf, const float* __restrict__ bihr,
                                 const float* __restrict__ bhhf, const float* __restrict__ bhhr,
                                 const float* __restrict__ lng, const float* __restrict__ lnb,
                                 float* __restrict__ env, float* __restrict__ cvec) {
    int w = threadIdx.x >> 6, lane = threadIdx.x & 63;
    int row = blockIdx.x * 4 + w;  // [0, 6144)
    int l = row / 1536;
    int n1536 = row - l * 1536;
    int dir = n1536 >= 768;
    int n = n1536 - dir * 768;  // [0,768), gate-stacked r|z|n
    const float* W = (dir ? wihr : wihf) + ((size_t)l * 768 + n) * 256 + lane * 4;
    float4 wv = *(const float4*)W;
    float4 gv = *(const float4*)(lng + l * 256 + lane * 4);
    float4 bv = *(const float4*)(lnb + l * 256 + lane * 4);
    float es = wv.x * gv.x + wv.y * gv.y + wv.z * gv.z + wv.w * gv.w;
    float cs = wv.x * bv.x + wv.y * bv.y + wv.z * bv.z + wv.w * bv.w;
#pragma unroll
    for (int off = 1; off < 64; off <<= 1) {
        es += __shfl_xor(es, off);
        cs += __shfl_xor(cs, off);
    }
    if (lane == 0) {
        float S = (n < 512) ? NL2E : P2L2E;
        float c = cs + (dir ? bihr : bihf)[l * 768 + n];
        if (n < 512) c += (dir ? bhhr : bhhf)[l * 768 + n];  // bhh_n stays in the scan
        env[row] = es * S;
        cvec[row] = c * S;
    }
}

// ---------- embedding (+ reverse-complement encode), h bf16 [e][b][s][k] ----------
__global__ void embed_kernel(const int* __restrict__ tok, const float* __restrict__ emb,
                             const float* __restrict__ pos, u16* __restrict__ h) {
    int row = blockIdx.x;  // e*32768 + b*1024 + s
    int k = threadIdx.x;
    int e = row >> 15;
    int rem = row & 32767;
    int b = rem >> 10;
    int s = rem & 1023;
    int t0 = (e == 0) ? tok[b * 1024 + s] : tok[b * 1024 + (1023 - s)];
    if (e == 1) t0 = (t0 < 4) ? (3 - t0) : 4;  // RC map {3,2,1,0,4}
    h[(size_t)row * 256 + k] = f2bf(emb[t0 * 256 + k] + pos[s * 256 + k]);
}

// ---------- per-row LN stats (mean, rstd) in m-order ----------
__global__ void ln_stats_kernel(const u16* __restrict__ h, float2* __restrict__ stats) {
    int w = threadIdx.x >> 6, lane = threadIdx.x & 63;
    int row = blockIdx.x * 4 + w;  // e*32768 + b*1024 + s
    int e = row >> 15;
    int rem = row & 32767;
    int b = rem >> 10;
    int s = rem & 1023;
    ushort4 v = *(const ushort4*)(h + (size_t)row * 256 + lane * 4);
    float x0 = bf2f(v.x), x1 = bf2f(v.y), x2 = bf2f(v.z), x3 = bf2f(v.w);
    float sum = x0 + x1 + x2 + x3;
    float sq = x0 * x0 + x1 * x1 + x2 * x2 + x3 * x3;
#pragma unroll
    for (int off = 1; off < 64; off <<= 1) {
        sum += __shfl_xor(sum, off);
        sq += __shfl_xor(sq, off);
    }
    if (lane == 0) {
        float mean = sum * (1.0f / 256.0f);
        float var = sq * (1.0f / 256.0f) - mean * mean;
        stats[e * 32768 + s * 32 + b] = make_float2(mean, rsqrtf(var + 1e-5f));
    }
}

// ---------- BT-GEMM: C[m][n] = sum_k A[m][k]*B[n][k], bf16 in / fp32 acc ----------
// OP 0: xi (N=1536,K=256): A = h (gathered b,s), LN folded via stats + env/cvec; out -> xi
// OP 1: gate(N=256,K=512): A = [f|r] from xi cols [0:256)/[768:1024); c -> xi cols [256:512)
// OP 2: out (N=256,K=256): A = c from xi cols [256:512); h += C + bias (bf16 RMW)
template <int OP>
__global__ __launch_bounds__(256, 2) void gemm_bt(
    const u16* __restrict__ hin, const u16* __restrict__ Bw,
    const float* __restrict__ bias0, const float* __restrict__ bias1,
    u16* xibuf, const float2* __restrict__ stats, u16* hres) {
    constexpr int KK = (OP == 1) ? 512 : 256;
    constexpr int NKB = KK / 64;
    __shared__ __align__(16) u16 As[2][128 * 64];
    __shared__ __align__(16) u16 Bs[2][128 * 64];
    const int tid = threadIdx.x;
    const int lane = tid & 63, w = tid >> 6;
    const int l15 = lane & 15, q = lane >> 4;
    const int l8 = lane & 7, r8 = lane >> 3;
    const int e = blockIdx.z;
    const int m0 = blockIdx.x * 128, n0 = blockIdx.y * 128;
    const int wm = w & 1, wn = w >> 1;

    uint4 ra[4], rb[4];
    auto loadS = [&](int kb) {
#pragma unroll
        for (int i = 0; i < 4; ++i) {
            int row = w * 32 + i * 8 + r8;
            int c = l8 ^ (row & 7);
            int mrow = m0 + row;
            const u16* ap;
            if constexpr (OP == 0) {
                int bb = mrow & 31, ss = mrow >> 5;
                ap = hin + ((size_t)e * 32768 + bb * 1024 + ss) * 256 + kb * 64;
            } else if constexpr (OP == 1) {
                int colbase = (kb >= 4) ? 768 : 0;
                ap = xibuf + (size_t)e * XE + (size_t)mrow * XROW + colbase + (kb & 3) * 64;
            } else {
                ap = xibuf + (size_t)e * XE + (size_t)mrow * XROW + 256 + kb * 64;
            }
            ra[i] = *(const uint4*)(ap + c * 8);
            rb[i] = *(const uint4*)(Bw + (size_t)(n0 + row) * KK + kb * 64 + c * 8);
        }
    };
    auto writeS = [&](int buf) {
#pragma unroll
        for (int i = 0; i < 4; ++i) {
            int row = w * 32 + i * 8 + r8;
            *(uint4*)&As[buf][row * 64 + l8 * 8] = ra[i];
            *(uint4*)&Bs[buf][row * 64 + l8 * 8] = rb[i];
        }
    };

    f32x4 acc[4][4];
#pragma unroll
    for (int i = 0; i < 4; ++i)
#pragma unroll
        for (int j = 0; j < 4; ++j) acc[i][j] = (f32x4){0.f, 0.f, 0.f, 0.f};

    loadS(0);
    writeS(0);
    for (int kb = 0; kb < NKB; ++kb) {
        if (kb + 1 < NKB) loadS(kb + 1);
        __syncthreads();
        const int buf = kb & 1;
#pragma unroll
        for (int kt = 0; kt < 2; ++kt) {
            bf16x8 af[4], bfr[4];
#pragma unroll
            for (int i = 0; i < 4; ++i) {
                int rowa = wm * 64 + i * 16 + l15;
                int rowb = wn * 64 + i * 16 + l15;
                int c = kt * 4 + q;
                af[i] = *(const bf16x8*)&As[buf][rowa * 64 + (c ^ (rowa & 7)) * 8];
                bfr[i] = *(const bf16x8*)&Bs[buf][rowb * 64 + (c ^ (rowb & 7)) * 8];
            }
#pragma unroll
            for (int i = 0; i < 4; ++i)
#pragma unroll
                for (int j = 0; j < 4; ++j) acc[i][j] = mfma16(af[i], bfr[j], acc[i][j]);
        }
        if (kb + 1 < NKB) writeS((kb + 1) & 1);
    }

#pragma unroll
    for (int i = 0; i < 4; ++i) {
        const int mb = m0 + wm * 64 + i * 16 + q * 4;
        float2 st[4];
        if constexpr (OP == 0) {
#pragma unroll
            for (int r = 0; r < 4; ++r) st[r] = stats[e * 32768 + mb + r];
        }
#pragma unroll
        for (int jt = 0; jt < 4; ++jt) {
            const int nn = n0 + wn * 64 + jt * 16 + l15;
            f32x4 a = acc[i][jt];
            if constexpr (OP == 0) {
                const float en = bias0[nn], cn = bias1[nn];
#pragma unroll
                for (int r = 0; r < 4; ++r) {
                    float val = a[r] * st[r].y - st[r].x * st[r].y * en + cn;
                    xibuf[(size_t)e * XE + (size_t)(mb + r) * XROW + nn] = f2bf(val);
                }
            } else if constexpr (OP == 1) {
                const float bs = bias0[nn];
#pragma unroll
                for (int r = 0; r < 4; ++r) {
                    u16* xr_ = xibuf + (size_t)e * XE + (size_t)(mb + r) * XROW;
                    float gg = sigf(a[r] + bs);
                    float fv = bf2f(xr_[nn]), rv = bf2f(xr_[768 + nn]);
                    xr_[256 + nn] = f2bf(gg * fv + (1.0f - gg) * rv);
                }
            } else {
                const float bs = bias0[nn];
#pragma unroll
                for (int r = 0; r < 4; ++r) {
                    const int mm = mb + r;
                    size_t idx = ((size_t)e * 32768 + (size_t)(mm & 31) * 1024 + (mm >> 5)) * 256 + nn;
                    hres[idx] = f2bf(bf2f(hres[idx]) + a[r] + bs);
                }
            }
        }
    }
}

// ---------- bidirectional GRU scan, single-WG-per-slice ----------
// EXACT round-3 structure (the empirically fastest configuration: single stride-264
// LDS buffer, two plain __syncthreads per step, global stores issued BEFORE sync1,
// xv prefetch after sync2, h_prev re-read from LDS). The ONLY delta vs round-3 is
// the epilogue arithmetic: weights/pre-activations arrive prescaled (-log2e for r/z,
// 2log2e for n), so sigmoid/tanh reduce to exp2+rcp directly on the accumulators.
// No register arrays with dynamic indices (round-6's scratch-spill trap), no
// batching, no barrier tricks.
__global__ __launch_bounds__(512, 2) void scan_kernel(
    u16* xi, const u16* __restrict__ whh,
    const float* __restrict__ bhhf, const float* __restrict__ bhhr) {
    __shared__ __align__(16) u16 h_lds[16 * 264];  // [m=16][k=256+8 pad]
    const int tid = threadIdx.x;
    const int w = tid >> 6, lane = tid & 63;
    const int l15 = lane & 15, q = lane >> 4;
    const int bid = blockIdx.x;
    const int bh = bid & 1, d = (bid >> 1) & 1, e = bid >> 2;
    const int jb = w * 32;

    // persistent weight A-frags: wf[g][jc][kt], row = g*256 + jb + jc*16 + l15, k = kt*32+q*8
    const u16* W = whh + (size_t)d * 196608;
    bf16x8 wf[3][2][8];
#pragma unroll
    for (int g = 0; g < 3; ++g)
#pragma unroll
        for (int jc = 0; jc < 2; ++jc)
#pragma unroll
            for (int kt = 0; kt < 8; ++kt)
                wf[g][jc][kt] = *(const bf16x8*)(
                    W + (size_t)(g * 256 + jb + jc * 16 + l15) * 256 + kt * 32 + q * 8);

    // n-gate bhh (inside r*(...)), prescaled by 2log2e
    const float* bnp = (d ? bhhr : bhhf) + 512;
    f32x4 bn[2];
#pragma unroll
    for (int jc = 0; jc < 2; ++jc)
#pragma unroll
        for (int r = 0; r < 4; ++r) bn[jc][r] = P2L2E * bnp[jb + jc * 16 + q * 4 + r];

    // xi pointer: row (s*32 + bh*16 + l15), col (d*768 + jb + q*4); imm offsets cover (g,jc)
    const int s0 = d ? 1023 : 0;
    const ptrdiff_t step = (d ? -32 : 32) * (ptrdiff_t)XROW;
    u16* p = xi + (size_t)e * XE + (size_t)(s0 * 32 + bh * 16 + l15) * XROW + d * 768 + jb + q * 4;

    const int lrow = l15 * 264;
    const int jcol = jb + q * 4;

    ushort4 xvv[3][2];
#pragma unroll
    for (int g = 0; g < 3; ++g)
#pragma unroll
        for (int jc = 0; jc < 2; ++jc)
            xvv[g][jc] = *(const ushort4*)(p + g * 256 + jc * 16);

    for (int t = 0; t < 1024; ++t) {
        f32x4 a0[2], a1[2], a2[2];
#pragma unroll
        for (int jc = 0; jc < 2; ++jc) {
            a0[jc] = (f32x4){0.f, 0.f, 0.f, 0.f};
            a1[jc] = (f32x4){0.f, 0.f, 0.f, 0.f};
            a2[jc] = bn[jc];
        }
        if (t > 0) {
#pragma unroll
            for (int kt = 0; kt < 8; ++kt) {
                bf16x8 hb = *(const bf16x8*)&h_lds[lrow + kt * 32 + q * 8];
#pragma unroll
                for (int jc = 0; jc < 2; ++jc) {
                    a0[jc] = mfma16(wf[0][jc][kt], hb, a0[jc]);
                    a1[jc] = mfma16(wf[1][jc][kt], hb, a1[jc]);
                    a2[jc] = mfma16(wf[2][jc][kt], hb, a2[jc]);
                }
            }
        }
        // epilogue: lane owns (m=l15, j = jb + jc*16 + q*4 + r); h_prev from LDS (R3 form)
        ushort4 hs[2];
#pragma unroll
        for (int jc = 0; jc < 2; ++jc) {
            ushort4 hp4 = (t > 0) ? *(const ushort4*)&h_lds[lrow + jcol + jc * 16]
                                  : (ushort4){0, 0, 0, 0};
            u16 hr[4];
#pragma unroll
            for (int r = 0; r < 4; ++r) {
                float xr = bf2f(((const u16*)&xvv[0][jc])[r]);  // prescaled by -log2e
                float xz = bf2f(((const u16*)&xvv[1][jc])[r]);  // prescaled by -log2e
                float xn = bf2f(((const u16*)&xvv[2][jc])[r]);  // prescaled by 2log2e
                float rg = __builtin_amdgcn_rcpf(1.0f + __builtin_amdgcn_exp2f(xr + a0[jc][r]));
                float zg = __builtin_amdgcn_rcpf(1.0f + __builtin_amdgcn_exp2f(xz + a1[jc][r]));
                float E = __builtin_amdgcn_exp2f(__builtin_fmaf(rg, a2[jc][r], xn));
                float ng = (E - 1.0f) * __builtin_amdgcn_rcpf(E + 1.0f);
                float hp = (t > 0) ? bf2f(((const u16*)&hp4)[r]) : 0.f;
                float h2 = __builtin_fmaf(zg, hp - ng, ng);
                hr[r] = f2bf(h2);
            }
            hs[jc] = (ushort4){hr[0], hr[1], hr[2], hr[3]};
        }
        // global state store (in-place into consumed xr columns of this row) — R3 placement
        *(ushort4*)(p + 0) = hs[0];
        *(ushort4*)(p + 16) = hs[1];
        __syncthreads();  // sync1: all reads of h_{t-1} done
        *(ushort4*)&h_lds[lrow + jcol] = hs[0];
        *(ushort4*)&h_lds[lrow + jcol + 16] = hs[1];
        __syncthreads();  // sync2: h_t visible
        if (t + 1 < 1024) {
            p += step;
#pragma unroll
            for (int g = 0; g < 3; ++g)
#pragma unroll
                for (int jc = 0; jc < 2; ++jc)
                    xvv[g][jc] = *(const ushort4*)(p + g * 256 + jc * 16);
        }
    }
}

// ---------- final LN + mean-pool + head (projection, LN, exact GELU) ----------
__global__ __launch_bounds__(256) void pool_head_kernel(
    const u16* __restrict__ h, const float* __restrict__ fng, const float* __restrict__ fnb,
    const float* __restrict__ pw, const float* __restrict__ pb,
    const float* __restrict__ plng, const float* __restrict__ plnb, float* __restrict__ out) {
    __shared__ float pacc[4][256];
    __shared__ float pooled[256];
    const int b = blockIdx.x;
    const int tid = threadIdx.x;
    const int w = tid >> 6, lane = tid & 63;
    float a0 = 0.f, a1 = 0.f, a2 = 0.f, a3 = 0.f;
    for (int rr = w; rr < 2048; rr += 4) {
        int e = rr >> 10, s = rr & 1023;
        const u16* src = h + ((size_t)e * 32768 + (size_t)b * 1024 + s) * 256 + lane * 4;
        ushort4 v = *(const ushort4*)src;
        float x0 = bf2f(v.x), x1 = bf2f(v.y), x2 = bf2f(v.z), x3 = bf2f(v.w);
        float sum = x0 + x1 + x2 + x3;
        float sq = x0 * x0 + x1 * x1 + x2 * x2 + x3 * x3;
#pragma unroll
        for (int off = 1; off < 64; off <<= 1) {
            sum += __shfl_xor(sum, off);
            sq += __shfl_xor(sq, off);
        }
        float mean = sum * (1.0f / 256.0f);
        float var = sq * (1.0f / 256.0f) - mean * mean;
        float rs = rsqrtf(var + 1e-5f);
        a0 += (x0 - mean) * rs;
        a1 += (x1 - mean) * rs;
        a2 += (x2 - mean) * rs;
        a3 += (x3 - mean) * rs;
    }
    pacc[w][lane * 4 + 0] = a0;
    pacc[w][lane * 4 + 1] = a1;
    pacc[w][lane * 4 + 2] = a2;
    pacc[w][lane * 4 + 3] = a3;
    __syncthreads();
    {
        int k = tid;
        float t = pacc[0][k] + pacc[1][k] + pacc[2][k] + pacc[3][k];
        pooled[k] = (t * fng[k] + 2048.0f * fnb[k]) * (0.5f / 1024.0f);
    }
    __syncthreads();
    if (tid < 64) {
        float p = pb[tid];
        const float* wrow = pw + tid * 256;
        for (int k = 0; k < 256; ++k) p += pooled[k] * wrow[k];
        float sum = p;
#pragma unroll
        for (int off = 1; off < 64; off <<= 1) sum += __shfl_xor(sum, off);
        float mean = sum * (1.0f / 64.0f);
        float dv = p - mean;
        float sq = dv * dv;
#pragma unroll
        for (int off = 1; off < 64; off <<= 1) sq += __shfl_xor(sq, off);
        float var = sq * (1.0f / 64.0f);
        float y = dv * rsqrtf(var + 1e-5f) * plng[tid] + plnb[tid];
        out[b * 64 + tid] = y * 0.5f * (1.0f + erff(y * 0.70710678118654752f));
    }
}

// ---------- host launch ----------
extern "C" void kernel_launch(void* const* d_in, const int* in_sizes, int n_in,
                              void* d_out, int out_size, void* d_ws, size_t ws_size,
                              hipStream_t stream) {
    (void)in_sizes; (void)n_in; (void)out_size; (void)ws_size;
    const int* tokens = (const int*)d_in[0];
    const float* emb = (const float*)d_in[1];
    const float* pos = (const float*)d_in[2];
    const float* ln_g = (const float*)d_in[3];
    const float* ln_b = (const float*)d_in[4];
    const float* wih_f = (const float*)d_in[5];
    const float* whh_f = (const float*)d_in[6];
    const float* bih_f = (const float*)d_in[7];
    const float* bhh_f = (const float*)d_in[8];
    const float* wih_r = (const float*)d_in[9];
    const float* whh_r = (const float*)d_in[10];
    const float* bih_r = (const float*)d_in[11];
    const float* bhh_r = (const float*)d_in[12];
    const float* wg = (const float*)d_in[13];
    const float* bg = (const float*)d_in[14];
    const float* wo = (const float*)d_in[15];
    const float* bo = (const float*)d_in[16];
    const float* fn_g = (const float*)d_in[17];
    const float* fn_b = (const float*)d_in[18];
    const float* pw = (const float*)d_in[19];
    const float* pb = (const float*)d_in[20];
    const float* pln_g = (const float*)d_in[21];
    const float* pln_b = (const float*)d_in[22];
    float* out = (float*)d_out;
    char* ws = (char*)d_ws;

    // workspace map (bytes) — total ~232 MiB
    u16* h = (u16*)(ws + 0);                    //  32 MiB bf16 [2][32][1024][256]
    u16* xi = (u16*)(ws + 33554432);            // 192 MiB bf16 [2][32768][1536]
    u16* wih_cat = (u16*)(ws + 234881024);      //   3 MiB [L][1536][256] (gamma+S folded)
    u16* whh_bf = (u16*)(ws + 238026752);       //   3 MiB [L][2][768][256] (S folded)
    u16* wg_bf = (u16*)(ws + 241172480);        //   1 MiB [L][256][512]
    u16* wo_bf = (u16*)(ws + 242221056);        // 0.5 MiB [L][256][256]
    float* env = (float*)(ws + 242745344);      //  24 KiB [L][1536]
    float* cvec = (float*)(ws + 242769920);     //  24 KiB [L][1536]
    float2* stats = (float2*)(ws + 242794496);  // 512 KiB [2][32768]

    convert_wih<<<3072, 256, 0, stream>>>(wih_f, ln_g, wih_cat, 0);
    convert_wih<<<3072, 256, 0, stream>>>(wih_r, ln_g, wih_cat, 196608);
    convert_whh<<<3072, 256, 0, stream>>>(whh_f, whh_bf, 0);
    convert_whh<<<3072, 256, 0, stream>>>(whh_r, whh_bf, 196608);
    convert_w<<<2048, 256, 0, stream>>>(wg, wg_bf, 131072, 131072, 524288);
    convert_w<<<1024, 256, 0, stream>>>(wo, wo_bf, 65536, 65536, 262144);
    head_vecs_kernel<<<1536, 256, 0, stream>>>(wih_f, wih_r, bih_f, bih_r, bhh_f, bhh_r,
                                               ln_g, ln_b, env, cvec);
    embed_kernel<<<65536, 256, 0, stream>>>(tokens, emb, pos, h);

    for (int i = 0; i < 4; ++i) {
        ln_stats_kernel<<<16384, 256, 0, stream>>>(h, stats);
        gemm_bt<0><<<dim3(256, 12, 2), 256, 0, stream>>>(
            h, wih_cat + (size_t)i * 393216, env + i * 1536, cvec + i * 1536,
            xi, stats, nullptr);
        scan_kernel<<<8, 512, 0, stream>>>(
            xi, whh_bf + (size_t)i * 393216, bhh_f + i * 768, bhh_r + i * 768);
        gemm_bt<1><<<dim3(256, 2, 2), 256, 0, stream>>>(
            nullptr, wg_bf + (size_t)i * 131072, bg + i * 256, nullptr,
            xi, nullptr, nullptr);
        gemm_bt<2><<<dim3(256, 2, 2), 256, 0, stream>>>(
            nullptr, wo_bf + (size_t)i * 65536, bo + i * 256, nullptr,
            xi, nullptr, h);
    }
    pool_head_kernel<<<32, 256, 0, stream>>>(h, fn_g, fn_b, pw, pb, pln_g, pln_b, out);
}